// Round 9
// baseline (414.363 us; speedup 1.0000x reference)
//
#include <hip/hip_runtime.h>
#include <stdint.h>

// GaitnetActor B=8192, OPT=16. Round 9: 4 blocks/CU decorrelation.
// k_front (256 blocks): bf16-convert tw1/tw2/uw2 into ws AND precompute
// se[8192][256] bf16 (shared MLP) into ws. k_main (4096 blocks, 256 thr,
// M=32 rows = 2 batch elems, LDS ~36 KB -> 4 blocks/CU): uniq L1 (VALU),
// uniq L2 (MFMA), trunk L1->L2 K-chunk-fused (MFMA), heads.
// bf16 MFMA / fp32 accum. out[0:131072]=logits fp32, [131072:]=duration.

static constexpr int B_ = 8192;

typedef __attribute__((ext_vector_type(8))) short bf16x8;
typedef __attribute__((ext_vector_type(4))) float f32x4;

__device__ __forceinline__ float u2f(uint16_t u) {
    union { uint32_t i; float f; } c; c.i = (uint32_t)u << 16; return c.f;
}
__device__ __forceinline__ uint16_t f2u(float f) {
    union { float f; uint32_t i; } c; c.f = f;
    uint32_t x = c.i;
    return (uint16_t)((x + 0x7FFFu + ((x >> 16) & 1u)) >> 16);
}
__device__ __forceinline__ bf16x8 cvt8(float4 a, float4 b) {
    bf16x8 r;
    r[0] = (short)f2u(a.x); r[1] = (short)f2u(a.y);
    r[2] = (short)f2u(a.z); r[3] = (short)f2u(a.w);
    r[4] = (short)f2u(b.x); r[5] = (short)f2u(b.y);
    r[6] = (short)f2u(b.z); r[7] = (short)f2u(b.w);
    return r;
}

// ws layout (uint16 elems): se[8192*256] | tw1 512x384 | tw2 256x512 | uw2 128x128
static constexpr int WSE  = 0;
static constexpr int WTW1 = 2097152;
static constexpr int WTW2 = WTW1 + 196608;   // 2293760
static constexpr int WUW2 = WTW2 + 131072;   // 2424832

// ---------------- k_front: weight conversion + shared-MLP precompute -------
__global__ __launch_bounds__(256) void k_front(
    const float* __restrict__ obs,
    const float* __restrict__ sw1, const float* __restrict__ sb1,
    const float* __restrict__ sw2f, const float* __restrict__ sb2,
    const float* __restrict__ tw1, const float* __restrict__ tw2,
    const float* __restrict__ uw2, uint16_t* __restrict__ ws)
{
    const int t = threadIdx.x;
    // part A: convert 1344 weight elems (336 float4s) per block
    #pragma unroll
    for (int i = t; i < 336; i += 256) {
        int g = (blockIdx.x * 336 + i) * 4;
        const float* src; int dst;
        if (g < 196608)      { src = tw1 + g;            dst = WTW1 + g; }
        else if (g < 327680) { src = tw2 + (g - 196608); dst = WTW2 + (g - 196608); }
        else                 { src = uw2 + (g - 327680); dst = WUW2 + (g - 327680); }
        float4 v = *reinterpret_cast<const float4*>(src);
        ushort4 o;
        o.x = f2u(v.x); o.y = f2u(v.y); o.z = f2u(v.z); o.w = f2u(v.w);
        *reinterpret_cast<ushort4*>(ws + dst) = o;
    }

    // part B: se for 32 batch elems
    __shared__ float xs[32][24];
    __shared__ uint16_t h1sf[32 * 264];
    const int b0 = blockIdx.x * 32;
    for (int i = t; i < 704; i += 256) {
        int e = i / 22, c = i - e * 22;
        xs[e][c] = obs[(size_t)(b0 + e) * 150 + c];
    }
    __syncthreads();
    {   // shared L1: neuron t, all 32 elems
        float w[22];
        #pragma unroll
        for (int k = 0; k < 22; ++k) w[k] = sw1[t * 22 + k];
        const float bias = sb1[t];
        #pragma unroll
        for (int e = 0; e < 32; ++e) {
            float a = bias;
            #pragma unroll
            for (int k = 0; k < 22; ++k) a += w[k] * xs[e][k];
            h1sf[e * 264 + t] = f2u(fmaxf(a, 0.f));
        }
    }
    __syncthreads();
    {   // shared L2 via MFMA: M=32 x N=256 (wave: N=64), K=256, fp32 B inline-cvt
        const int wv = t >> 6, lane = t & 63, quad = lane >> 4, l16 = lane & 15;
        f32x4 acc[2][4];
        #pragma unroll
        for (int nt = 0; nt < 4; ++nt) {
            float bv = sb2[wv * 64 + nt * 16 + l16];
            acc[0][nt] = {bv, bv, bv, bv};
            acc[1][nt] = {bv, bv, bv, bv};
        }
        #pragma unroll
        for (int kk = 0; kk < 8; ++kk) {
            bf16x8 af[2];
            #pragma unroll
            for (int mt = 0; mt < 2; ++mt)
                af[mt] = *reinterpret_cast<const bf16x8*>(
                    &h1sf[(mt * 16 + l16) * 264 + kk * 32 + quad * 8]);
            #pragma unroll
            for (int nt = 0; nt < 4; ++nt) {
                const float* wr = sw2f + (wv * 64 + nt * 16 + l16) * 256 + kk * 32 + quad * 8;
                float4 a = *reinterpret_cast<const float4*>(wr);
                float4 b = *reinterpret_cast<const float4*>(wr + 4);
                bf16x8 bf = cvt8(a, b);
                #pragma unroll
                for (int mt = 0; mt < 2; ++mt)
                    acc[mt][nt] = __builtin_amdgcn_mfma_f32_16x16x32_bf16(
                        af[mt], bf, acc[mt][nt], 0, 0, 0);
            }
        }
        #pragma unroll
        for (int mt = 0; mt < 2; ++mt)
            #pragma unroll
            for (int nt = 0; nt < 4; ++nt)
                #pragma unroll
                for (int r = 0; r < 4; ++r) {
                    int row = mt * 16 + quad * 4 + r;      // = batch elem idx
                    int n = wv * 64 + nt * 16 + l16;
                    ws[WSE + (size_t)(b0 + row) * 256 + n] =
                        f2u(fmaxf(acc[mt][nt][r], 0.f));
                }
    }
}

// ---------------- k_main: per-2-elem fused uniq + trunk --------------------
// LDS (bytes): uq float[2][132]=1056 | noop float[32]=128 @1056 | seb bf16[2][264]
// @1184 (1056B) | h1u bf16[32][136] @2240 (8704) | uet @10944 (8704) |
// h1t bf16[32][264] @19648 (16896, t2 overlays) -> 36544 B, 4 blocks/CU.
static constexpr int UQ_OFF   = 0;
static constexpr int NOOP_OFF = 1056;
static constexpr int SEB_OFF  = 1184;
static constexpr int H1U_OFF  = 2240;
static constexpr int UET_OFF  = 10944;
static constexpr int H1T_OFF  = 19648;
static constexpr int SMEM_SZ  = 36544;

__global__ __launch_bounds__(256, 4) void k_main(
    const float* __restrict__ obs,
    const float* __restrict__ uw1, const float* __restrict__ ub1,
    const float* __restrict__ ub2, const float* __restrict__ emb,
    const float* __restrict__ tb1, const float* __restrict__ tb2,
    const float* __restrict__ vw,  const float* __restrict__ vb,
    const float* __restrict__ dw,  const float* __restrict__ db,
    const uint16_t* __restrict__ wsb,
    float* __restrict__ out)
{
    __shared__ __align__(16) char smem[SMEM_SZ];
    float*    uq    = (float*)(smem + UQ_OFF);
    float*    noopf = (float*)(smem + NOOP_OFF);
    uint16_t* seb   = (uint16_t*)(smem + SEB_OFF);
    uint16_t* h1u   = (uint16_t*)(smem + H1U_OFF);
    uint16_t* uet   = (uint16_t*)(smem + UET_OFF);
    uint16_t* h1t   = (uint16_t*)(smem + H1T_OFF);
    uint16_t* t2    = h1t;   // overlay after main loop

    const int t    = threadIdx.x;
    const int wv   = t >> 6;        // 0..3
    const int lane = t & 63;
    const int quad = lane >> 4;
    const int l16  = lane & 15;
    const int b0   = blockIdx.x * 2;

    const uint16_t* seg  = wsb + WSE;
    const uint16_t* tw1b = wsb + WTW1;
    const uint16_t* tw2b = wsb + WTW2;
    const uint16_t* uw2b = wsb + WUW2;

    // ---- stage 1: uq obs cols, noop flags, seb rows ----
    {
        int e = t >> 7, c = t & 127;
        uq[e * 132 + c] = obs[(size_t)(b0 + e) * 150 + 22 + c];
        ((uint32_t*)seb)[e * 132 + c] =
            ((const uint32_t*)(seg + (size_t)(b0 + e) * 256))[c];
        if (t < 32) {
            int ee = t >> 4, o = t & 15;
            noopf[t] = (obs[(size_t)(b0 + ee) * 150 + 22 + o * 8] == 1.0f) ? 1.0f : 0.0f;
        }
    }
    __syncthreads();

    // ---- stage 2: unique L1 (VALU): 32 rows x 128 neurons ----
    {
        const int n = t & 127, h = t >> 7;
        float w[8];
        #pragma unroll
        for (int k = 0; k < 8; ++k) w[k] = uw1[n * 8 + k];
        const float bias = ub1[n];
        #pragma unroll
        for (int ii = 0; ii < 16; ++ii) {
            int row = h * 16 + ii;                 // e = h, o = ii
            const float4* xp = (const float4*)&uq[h * 132 + ii * 8];
            float4 xa = xp[0], xb = xp[1];
            float a = bias + w[0] * xa.x + w[1] * xa.y + w[2] * xa.z + w[3] * xa.w
                           + w[4] * xb.x + w[5] * xb.y + w[6] * xb.z + w[7] * xb.w;
            h1u[row * 136 + n] = f2u(fmaxf(a, 0.f));
        }
    }
    __syncthreads();

    // ---- stage 3: unique L2 via MFMA (wave: M=32 x N=32), K=128 -> uet ----
    {
        f32x4 acc[2][2];
        float ev[2];
        #pragma unroll
        for (int nt = 0; nt < 2; ++nt) {
            int n = wv * 32 + nt * 16 + l16;
            float bv = ub2[n];
            ev[nt] = emb[n];
            acc[0][nt] = {bv, bv, bv, bv};
            acc[1][nt] = {bv, bv, bv, bv};
        }
        #pragma unroll
        for (int kk = 0; kk < 4; ++kk) {
            bf16x8 bfr[2];
            #pragma unroll
            for (int nt = 0; nt < 2; ++nt)
                bfr[nt] = *reinterpret_cast<const bf16x8*>(
                    &uw2b[(wv * 32 + nt * 16 + l16) * 128 + kk * 32 + quad * 8]);
            bf16x8 af[2];
            #pragma unroll
            for (int mt = 0; mt < 2; ++mt)
                af[mt] = *reinterpret_cast<const bf16x8*>(
                    &h1u[(mt * 16 + l16) * 136 + kk * 32 + quad * 8]);
            #pragma unroll
            for (int mt = 0; mt < 2; ++mt)
                #pragma unroll
                for (int nt = 0; nt < 2; ++nt)
                    acc[mt][nt] = __builtin_amdgcn_mfma_f32_16x16x32_bf16(
                        af[mt], bfr[nt], acc[mt][nt], 0, 0, 0);
        }
        #pragma unroll
        for (int mt = 0; mt < 2; ++mt)
            #pragma unroll
            for (int nt = 0; nt < 2; ++nt)
                #pragma unroll
                for (int r = 0; r < 4; ++r) {
                    int row = mt * 16 + quad * 4 + r;
                    float v = (noopf[row] != 0.0f) ? ev[nt] : fmaxf(acc[mt][nt][r], 0.f);
                    uet[row * 136 + wv * 32 + nt * 16 + l16] = f2u(v);
                }
    }
    __syncthreads();

    // ---- trunk: 2 N-chunks of 256, L1 -> (barrier) -> L2 accumulate ----
    f32x4 acc2[2][4];                   // trunk L2: M=32 x N=64 / wave
    #pragma unroll
    for (int nt = 0; nt < 4; ++nt) {
        float bv = tb2[wv * 64 + nt * 16 + l16];
        acc2[0][nt] = {bv, bv, bv, bv};
        acc2[1][nt] = {bv, bv, bv, bv};
    }

    #pragma unroll
    for (int nc = 0; nc < 2; ++nc) {
        // ---- L1 chunk: M=32 x N=256, K=384; wave = M32 x N64 ----
        {
            const int n0 = nc * 256 + wv * 64;
            f32x4 acc1[2][4];
            #pragma unroll
            for (int nt = 0; nt < 4; ++nt) {
                float bv = tb1[n0 + nt * 16 + l16];
                acc1[0][nt] = {bv, bv, bv, bv};
                acc1[1][nt] = {bv, bv, bv, bv};
            }
            const uint16_t* bb = tw1b + (n0 + l16) * 384 + quad * 8;
            bf16x8 bc[4], bn[4];
            #pragma unroll
            for (int nt = 0; nt < 4; ++nt)
                bc[nt] = *reinterpret_cast<const bf16x8*>(bb + nt * 6144);
            #pragma unroll
            for (int kk = 0; kk < 12; ++kk) {
                if (kk < 11) {
                    #pragma unroll
                    for (int nt = 0; nt < 4; ++nt)
                        bn[nt] = *reinterpret_cast<const bf16x8*>(
                            bb + nt * 6144 + (kk + 1) * 32);
                }
                bf16x8 af[2];
                if (kk < 8) {                       // A = seb broadcast (e = mt)
                    #pragma unroll
                    for (int mt = 0; mt < 2; ++mt)
                        af[mt] = *reinterpret_cast<const bf16x8*>(
                            &seb[mt * 264 + kk * 32 + quad * 8]);
                } else {                            // A = uet rows
                    #pragma unroll
                    for (int mt = 0; mt < 2; ++mt)
                        af[mt] = *reinterpret_cast<const bf16x8*>(
                            &uet[(mt * 16 + l16) * 136 + (kk - 8) * 32 + quad * 8]);
                }
                #pragma unroll
                for (int mt = 0; mt < 2; ++mt)
                    #pragma unroll
                    for (int nt = 0; nt < 4; ++nt)
                        acc1[mt][nt] = __builtin_amdgcn_mfma_f32_16x16x32_bf16(
                            af[mt], bc[nt], acc1[mt][nt], 0, 0, 0);
                #pragma unroll
                for (int nt = 0; nt < 4; ++nt) bc[nt] = bn[nt];
            }
            #pragma unroll
            for (int mt = 0; mt < 2; ++mt)
                #pragma unroll
                for (int nt = 0; nt < 4; ++nt)
                    #pragma unroll
                    for (int r = 0; r < 4; ++r) {
                        int row = mt * 16 + quad * 4 + r;
                        h1t[row * 264 + wv * 64 + nt * 16 + l16] =
                            f2u(fmaxf(acc1[mt][nt][r], 0.f));
                    }
        }
        __syncthreads();                            // h1t chunk ready
        // ---- L2 accumulate: K-chunk of 256; wave = M32 x N64 ----
        {
            const uint16_t* cb = tw2b + (wv * 64 + l16) * 512 + nc * 256 + quad * 8;
            bf16x8 cc[4], cn[4];
            #pragma unroll
            for (int nt = 0; nt < 4; ++nt)
                cc[nt] = *reinterpret_cast<const bf16x8*>(cb + nt * 8192);
            #pragma unroll
            for (int k2 = 0; k2 < 8; ++k2) {
                if (k2 < 7) {
                    #pragma unroll
                    for (int nt = 0; nt < 4; ++nt)
                        cn[nt] = *reinterpret_cast<const bf16x8*>(
                            cb + nt * 8192 + (k2 + 1) * 32);
                }
                bf16x8 af[2];
                #pragma unroll
                for (int mt = 0; mt < 2; ++mt)
                    af[mt] = *reinterpret_cast<const bf16x8*>(
                        &h1t[(mt * 16 + l16) * 264 + k2 * 32 + quad * 8]);
                #pragma unroll
                for (int mt = 0; mt < 2; ++mt)
                    #pragma unroll
                    for (int nt = 0; nt < 4; ++nt)
                        acc2[mt][nt] = __builtin_amdgcn_mfma_f32_16x16x32_bf16(
                            af[mt], cc[nt], acc2[mt][nt], 0, 0, 0);
                #pragma unroll
                for (int nt = 0; nt < 4; ++nt) cc[nt] = cn[nt];
            }
        }
        if (nc == 0) __syncthreads();               // h1t consumed before reuse
    }
    __syncthreads();                                // all h1t reads done
    // ---- t2 epilogue (overlays h1t) ----
    #pragma unroll
    for (int mt = 0; mt < 2; ++mt)
        #pragma unroll
        for (int nt = 0; nt < 4; ++nt)
            #pragma unroll
            for (int r = 0; r < 4; ++r) {
                int row = mt * 16 + quad * 4 + r;
                t2[row * 264 + wv * 64 + nt * 16 + l16] =
                    f2u(fmaxf(acc2[mt][nt][r], 0.f));
            }
    __syncthreads();

    // ---- heads: wave wv does rows 8wv..8wv+7 ----
    {
        float vwf[4], dwf[4];
        #pragma unroll
        for (int j = 0; j < 4; ++j) {
            vwf[j] = vw[lane + 64 * j];
            dwf[j] = dw[lane + 64 * j];
        }
        const float vbf = vb[0], dbf = db[0];
        #pragma unroll
        for (int rr = 0; rr < 8; ++rr) {
            int row = wv * 8 + rr;
            float sv = 0.f, sd = 0.f;
            #pragma unroll
            for (int j = 0; j < 4; ++j) {
                float tv = u2f(t2[row * 264 + lane + 64 * j]);
                sv += tv * vwf[j];
                sd += tv * dwf[j];
            }
            #pragma unroll
            for (int off = 32; off > 0; off >>= 1) {
                sv += __shfl_down(sv, off);
                sd += __shfl_down(sd, off);
            }
            if (lane == 0) {
                int g = blockIdx.x * 32 + row;
                out[g] = sv + vbf;
                float z = sd + dbf;
                float sig = 1.f / (1.f + __expf(-z));
                out[B_ * 16 + g] = sig * 0.4f + 0.1f;
            }
        }
    }
}

extern "C" void kernel_launch(void* const* d_in, const int* in_sizes, int n_in,
                              void* d_out, int out_size, void* d_ws, size_t ws_size,
                              hipStream_t stream) {
    const float* obs = (const float*)d_in[0];
    const float* sw1 = (const float*)d_in[1];
    const float* sb1 = (const float*)d_in[2];
    const float* sw2 = (const float*)d_in[3];
    const float* sb2 = (const float*)d_in[4];
    const float* uw1 = (const float*)d_in[5];
    const float* ub1 = (const float*)d_in[6];
    const float* uw2 = (const float*)d_in[7];
    const float* ub2 = (const float*)d_in[8];
    const float* emb = (const float*)d_in[9];
    const float* tw1 = (const float*)d_in[10];
    const float* tb1 = (const float*)d_in[11];
    const float* tw2 = (const float*)d_in[12];
    const float* tb2 = (const float*)d_in[13];
    const float* vw  = (const float*)d_in[14];
    const float* vb  = (const float*)d_in[15];
    const float* dw  = (const float*)d_in[16];
    const float* db  = (const float*)d_in[17];

    uint16_t* wsb = (uint16_t*)d_ws;

    k_front<<<256, 256, 0, stream>>>(obs, sw1, sb1, sw2, sb2, tw1, tw2, uw2, wsb);
    k_main<<<B_ / 2, 256, 0, stream>>>(obs, uw1, ub1, ub2, emb,
                                       tb1, tb2, vw, vb, dw, db, wsb,
                                       (float*)d_out);
}

// Round 10
// 258.709 us; speedup vs baseline: 1.6017x; 1.6017x over previous
//
#include <hip/hip_runtime.h>
#include <stdint.h>

// GaitnetActor B=8192, OPT=16. Round 10: algebraic cut — trunk-L1's se-part
// (K=0..255) is option-independent; precompute cse[b] = se[b]@W1se^T + tb1
// once per batch elem in k_front (saves 30 GFLOP of the 92). k_main (M=64,
// 512 thr, 2 blocks/CU) trunk-L1 runs K=128 (ue-part) with acc init = cse.
// bf16 MFMA / fp32 accum. out[0:131072]=logits fp32, [131072:]=duration.

static constexpr int B_ = 8192;

typedef __attribute__((ext_vector_type(8))) short bf16x8;
typedef __attribute__((ext_vector_type(4))) float f32x4;

__device__ __forceinline__ float u2f(uint16_t u) {
    union { uint32_t i; float f; } c; c.i = (uint32_t)u << 16; return c.f;
}
__device__ __forceinline__ uint16_t f2u(float f) {
    union { float f; uint32_t i; } c; c.f = f;
    uint32_t x = c.i;
    return (uint16_t)((x + 0x7FFFu + ((x >> 16) & 1u)) >> 16);
}
__device__ __forceinline__ bf16x8 cvt8(float4 a, float4 b) {
    bf16x8 r;
    r[0] = (short)f2u(a.x); r[1] = (short)f2u(a.y);
    r[2] = (short)f2u(a.z); r[3] = (short)f2u(a.w);
    r[4] = (short)f2u(b.x); r[5] = (short)f2u(b.y);
    r[6] = (short)f2u(b.z); r[7] = (short)f2u(b.w);
    return r;
}

// ws layout (uint16 elems): cse bf16 [8192][512] | tw1ue bf16 [512][128] |
// tw2 bf16 [256][512] | uw2 bf16 [128][128]  -> 8.81 MB total
static constexpr size_t WCSE   = 0;
static constexpr size_t WTW1UE = 4194304;
static constexpr size_t WTW2   = WTW1UE + 65536;    // 4259840
static constexpr size_t WUW2   = WTW2 + 131072;     // 4390912

// ---------------- k_front: weight cvt + se + cse precompute ----------------
__global__ __launch_bounds__(256) void k_front(
    const float* __restrict__ obs,
    const float* __restrict__ sw1, const float* __restrict__ sb1,
    const float* __restrict__ sw2f, const float* __restrict__ sb2,
    const float* __restrict__ tw1, const float* __restrict__ tb1,
    const float* __restrict__ tw2, const float* __restrict__ uw2,
    uint16_t* __restrict__ ws)
{
    __shared__ float xs[32][24];
    __shared__ uint16_t h1sf[32 * 264];
    __shared__ uint16_t seL[32 * 264];
    const int t = threadIdx.x;

    // part A: convert 53248 float4s total (208/block): tw1ue | tw2 | uw2
    if (t < 208) {
        int g4 = blockIdx.x * 208 + t;
        const float* src; size_t dst;
        if (g4 < 16384) {                 // tw1 ue-part: k in [256,384)
            int n = g4 >> 5, w = g4 & 31;
            src = tw1 + (size_t)(n * 96 + 64 + w) * 4;
            dst = WTW1UE + (size_t)(n * 32 + w) * 4;
        } else if (g4 < 49152) {
            int q = g4 - 16384;
            src = tw2 + (size_t)q * 4; dst = WTW2 + (size_t)q * 4;
        } else {
            int q = g4 - 49152;
            src = uw2 + (size_t)q * 4; dst = WUW2 + (size_t)q * 4;
        }
        float4 v = *reinterpret_cast<const float4*>(src);
        ushort4 o;
        o.x = f2u(v.x); o.y = f2u(v.y); o.z = f2u(v.z); o.w = f2u(v.w);
        *reinterpret_cast<ushort4*>(ws + dst) = o;
    }

    // part B: se then cse for 32 batch elems
    const int b0 = blockIdx.x * 32;
    for (int i = t; i < 704; i += 256) {
        int e = i / 22, c = i - e * 22;
        xs[e][c] = obs[(size_t)(b0 + e) * 150 + c];
    }
    __syncthreads();
    {   // shared L1: neuron t, 32 elems
        float w[22];
        #pragma unroll
        for (int k = 0; k < 22; ++k) w[k] = sw1[t * 22 + k];
        const float bias = sb1[t];
        #pragma unroll
        for (int e = 0; e < 32; ++e) {
            float a = bias;
            #pragma unroll
            for (int k = 0; k < 22; ++k) a += w[k] * xs[e][k];
            h1sf[e * 264 + t] = f2u(fmaxf(a, 0.f));
        }
    }
    __syncthreads();
    const int wv = t >> 6, lane = t & 63, quad = lane >> 4, l16 = lane & 15;
    {   // shared L2 (MFMA, B=fp32 inline cvt): M=32 x N=256, K=256 -> seL
        f32x4 acc[2][4];
        #pragma unroll
        for (int nt = 0; nt < 4; ++nt) {
            float bv = sb2[wv * 64 + nt * 16 + l16];
            acc[0][nt] = {bv, bv, bv, bv};
            acc[1][nt] = {bv, bv, bv, bv};
        }
        #pragma unroll
        for (int kk = 0; kk < 8; ++kk) {
            bf16x8 af[2];
            #pragma unroll
            for (int mt = 0; mt < 2; ++mt)
                af[mt] = *reinterpret_cast<const bf16x8*>(
                    &h1sf[(mt * 16 + l16) * 264 + kk * 32 + quad * 8]);
            #pragma unroll
            for (int nt = 0; nt < 4; ++nt) {
                const float* wr = sw2f + (size_t)(wv * 64 + nt * 16 + l16) * 256
                                  + kk * 32 + quad * 8;
                bf16x8 bf = cvt8(*reinterpret_cast<const float4*>(wr),
                                 *reinterpret_cast<const float4*>(wr + 4));
                #pragma unroll
                for (int mt = 0; mt < 2; ++mt)
                    acc[mt][nt] = __builtin_amdgcn_mfma_f32_16x16x32_bf16(
                        af[mt], bf, acc[mt][nt], 0, 0, 0);
            }
        }
        #pragma unroll
        for (int mt = 0; mt < 2; ++mt)
            #pragma unroll
            for (int nt = 0; nt < 4; ++nt)
                #pragma unroll
                for (int r = 0; r < 4; ++r)
                    seL[(mt * 16 + quad * 4 + r) * 264 + wv * 64 + nt * 16 + l16] =
                        f2u(fmaxf(acc[mt][nt][r], 0.f));
    }
    __syncthreads();
    {   // cse = seL @ W1se^T + tb1: M=32, N=512, K=256 (B=fp32 inline cvt)
        f32x4 acc[2][8];
        #pragma unroll
        for (int nt = 0; nt < 8; ++nt) {
            float bv = tb1[wv * 128 + nt * 16 + l16];
            acc[0][nt] = {bv, bv, bv, bv};
            acc[1][nt] = {bv, bv, bv, bv};
        }
        #pragma unroll
        for (int kk = 0; kk < 8; ++kk) {
            bf16x8 af[2];
            #pragma unroll
            for (int mt = 0; mt < 2; ++mt)
                af[mt] = *reinterpret_cast<const bf16x8*>(
                    &seL[(mt * 16 + l16) * 264 + kk * 32 + quad * 8]);
            #pragma unroll
            for (int nt = 0; nt < 8; ++nt) {
                const float* wr = tw1 + (size_t)(wv * 128 + nt * 16 + l16) * 384
                                  + kk * 32 + quad * 8;   // k < 256: se-part
                bf16x8 bf = cvt8(*reinterpret_cast<const float4*>(wr),
                                 *reinterpret_cast<const float4*>(wr + 4));
                #pragma unroll
                for (int mt = 0; mt < 2; ++mt)
                    acc[mt][nt] = __builtin_amdgcn_mfma_f32_16x16x32_bf16(
                        af[mt], bf, acc[mt][nt], 0, 0, 0);
            }
        }
        // NO relu — cse is a pre-activation partial sum
        #pragma unroll
        for (int mt = 0; mt < 2; ++mt)
            #pragma unroll
            for (int nt = 0; nt < 8; ++nt)
                #pragma unroll
                for (int r = 0; r < 4; ++r)
                    ws[WCSE + (size_t)(b0 + mt * 16 + quad * 4 + r) * 512 +
                       wv * 128 + nt * 16 + l16] = f2u(acc[mt][nt][r]);
    }
}

// ---------------- k_main ---------------------------------------------------
// LDS (bytes): uq f32[4][132]=2112 | noop f32[64] @2112 | cse bf16[4][512]
// @2368 (4096) | h1u bf16[64][136] @6464 | uet @23872 | h1t bf16[64][264]
// @41280 (t2 overlays) -> 75072 B, 2 blocks/CU.
static constexpr int UQ_OFF   = 0;
static constexpr int NOOP_OFF = 2112;
static constexpr int CSE_OFF  = 2368;
static constexpr int H1U_OFF  = 6464;
static constexpr int UET_OFF  = 23872;
static constexpr int H1T_OFF  = 41280;
static constexpr int SMEM_SZ  = 75072;

__global__ __launch_bounds__(512, 4) void k_main(
    const float* __restrict__ obs,
    const float* __restrict__ uw1, const float* __restrict__ ub1,
    const float* __restrict__ ub2, const float* __restrict__ emb,
    const float* __restrict__ tb2,
    const float* __restrict__ vw,  const float* __restrict__ vb,
    const float* __restrict__ dw,  const float* __restrict__ db,
    const uint16_t* __restrict__ wsb,
    float* __restrict__ out)
{
    __shared__ __align__(16) char smem[SMEM_SZ];
    float*    uq    = (float*)(smem + UQ_OFF);
    float*    noopf = (float*)(smem + NOOP_OFF);
    uint16_t* cseL  = (uint16_t*)(smem + CSE_OFF);
    uint16_t* h1u   = (uint16_t*)(smem + H1U_OFF);
    uint16_t* uet   = (uint16_t*)(smem + UET_OFF);
    uint16_t* h1t   = (uint16_t*)(smem + H1T_OFF);
    uint16_t* t2    = h1t;   // overlay after main loop

    const int t    = threadIdx.x;
    const int wv   = t >> 6;        // 0..7
    const int lane = t & 63;
    const int quad = lane >> 4;
    const int l16  = lane & 15;
    const int b0   = blockIdx.x * 4;

    const uint16_t* csep  = wsb + WCSE;
    const uint16_t* tw1ue = wsb + WTW1UE;
    const uint16_t* tw2b  = wsb + WTW2;
    const uint16_t* uw2b  = wsb + WUW2;

    // ---- stage 1: uniq obs cols, noop flags, cse rows ----
    {
        int e = t >> 7, c = t & 127;
        uq[e * 132 + c] = obs[(size_t)(b0 + e) * 150 + 22 + c];
        #pragma unroll
        for (int ii = 0; ii < 2; ++ii) {
            int i = t + ii * 512;            // 1024 u32 copies of cse
            int ee = i >> 8, cc = i & 255;
            ((uint32_t*)cseL)[ee * 256 + cc] =
                ((const uint32_t*)(csep + (size_t)(b0 + ee) * 512))[cc];
        }
        if (t < 64) {
            int ee = t >> 4, o = t & 15;
            noopf[t] = (obs[(size_t)(b0 + ee) * 150 + 22 + o * 8] == 1.0f) ? 1.0f : 0.0f;
        }
    }
    __syncthreads();

    // ---- stage 2: unique L1 (VALU): 64 rows x 128 neurons ----
    {
        const int n = t & 127, h = t >> 7;   // h = batch elem 0..3
        float w[8];
        #pragma unroll
        for (int k = 0; k < 8; ++k) w[k] = uw1[n * 8 + k];
        const float bias = ub1[n];
        #pragma unroll
        for (int ii = 0; ii < 16; ++ii) {
            int row = h * 16 + ii;
            const float4* xp = (const float4*)&uq[h * 132 + ii * 8];
            float4 xa = xp[0], xb = xp[1];
            float a = bias + w[0] * xa.x + w[1] * xa.y + w[2] * xa.z + w[3] * xa.w
                           + w[4] * xb.x + w[5] * xb.y + w[6] * xb.z + w[7] * xb.w;
            h1u[row * 136 + n] = f2u(fmaxf(a, 0.f));
        }
    }
    __syncthreads();

    // ---- stage 3: unique L2 via MFMA (wave: M=64 x N=16), K=128 -> uet ----
    {
        const int n = wv * 16 + l16;
        const float bv = ub2[n];
        const float ev = emb[n];
        f32x4 acc[4];
        #pragma unroll
        for (int mt = 0; mt < 4; ++mt) acc[mt] = {bv, bv, bv, bv};
        #pragma unroll
        for (int kk = 0; kk < 4; ++kk) {
            bf16x8 bf = *reinterpret_cast<const bf16x8*>(
                &uw2b[(size_t)n * 128 + kk * 32 + quad * 8]);
            #pragma unroll
            for (int mt = 0; mt < 4; ++mt) {
                bf16x8 af = *reinterpret_cast<const bf16x8*>(
                    &h1u[(mt * 16 + l16) * 136 + kk * 32 + quad * 8]);
                acc[mt] = __builtin_amdgcn_mfma_f32_16x16x32_bf16(af, bf, acc[mt], 0, 0, 0);
            }
        }
        #pragma unroll
        for (int mt = 0; mt < 4; ++mt)
            #pragma unroll
            for (int r = 0; r < 4; ++r) {
                int row = mt * 16 + quad * 4 + r;
                float v = (noopf[row] != 0.0f) ? ev : fmaxf(acc[mt][r], 0.f);
                uet[row * 136 + n] = f2u(v);
            }
    }
    __syncthreads();

    // ---- trunk: 2 N-chunks of 256; L1 (K=128, acc init = cse) -> L2 ----
    f32x4 acc2[4][2];                   // trunk L2: M=64 x N=32 / wave
    #pragma unroll
    for (int nt = 0; nt < 2; ++nt) {
        float bv = tb2[wv * 32 + nt * 16 + l16];
        #pragma unroll
        for (int mt = 0; mt < 4; ++mt) acc2[mt][nt] = {bv, bv, bv, bv};
    }

    #pragma unroll
    for (int nc = 0; nc < 2; ++nc) {
        // ---- L1 chunk: M=64 x N=256, K=128 (ue only); wave = M64 x N32 ----
        {
            f32x4 acc1[4][2];
            #pragma unroll
            for (int nt = 0; nt < 2; ++nt) {
                int n = nc * 256 + wv * 32 + nt * 16 + l16;
                #pragma unroll
                for (int mt = 0; mt < 4; ++mt) {     // cse broadcast: e = mt
                    float v = u2f(cseL[mt * 512 + n]);
                    acc1[mt][nt] = {v, v, v, v};
                }
            }
            const uint16_t* bb = tw1ue + (size_t)(nc * 256 + wv * 32 + l16) * 128
                                 + quad * 8;
            bf16x8 bc[2], bn[2];
            bc[0] = *reinterpret_cast<const bf16x8*>(bb);
            bc[1] = *reinterpret_cast<const bf16x8*>(bb + 2048);
            #pragma unroll
            for (int kk = 0; kk < 4; ++kk) {
                if (kk < 3) {
                    bn[0] = *reinterpret_cast<const bf16x8*>(bb + (kk + 1) * 32);
                    bn[1] = *reinterpret_cast<const bf16x8*>(bb + 2048 + (kk + 1) * 32);
                }
                bf16x8 af[4];
                #pragma unroll
                for (int mt = 0; mt < 4; ++mt)
                    af[mt] = *reinterpret_cast<const bf16x8*>(
                        &uet[(mt * 16 + l16) * 136 + kk * 32 + quad * 8]);
                #pragma unroll
                for (int mt = 0; mt < 4; ++mt)
                    #pragma unroll
                    for (int nt = 0; nt < 2; ++nt)
                        acc1[mt][nt] = __builtin_amdgcn_mfma_f32_16x16x32_bf16(
                            af[mt], bc[nt], acc1[mt][nt], 0, 0, 0);
                bc[0] = bn[0]; bc[1] = bn[1];
            }
            #pragma unroll
            for (int mt = 0; mt < 4; ++mt)
                #pragma unroll
                for (int nt = 0; nt < 2; ++nt)
                    #pragma unroll
                    for (int r = 0; r < 4; ++r) {
                        int row = mt * 16 + quad * 4 + r;
                        h1t[row * 264 + wv * 32 + nt * 16 + l16] =
                            f2u(fmaxf(acc1[mt][nt][r], 0.f));
                    }
        }
        __syncthreads();                            // h1t chunk ready
        // ---- L2 accumulate: K-chunk of 256; wave = M64 x N32 ----
        {
            const uint16_t* cb = tw2b + (size_t)(wv * 32 + l16) * 512 + nc * 256
                                 + quad * 8;
            bf16x8 cc[2], cn[2];
            cc[0] = *reinterpret_cast<const bf16x8*>(cb);
            cc[1] = *reinterpret_cast<const bf16x8*>(cb + 8192);
            #pragma unroll
            for (int k2 = 0; k2 < 8; ++k2) {
                if (k2 < 7) {
                    cn[0] = *reinterpret_cast<const bf16x8*>(cb + (k2 + 1) * 32);
                    cn[1] = *reinterpret_cast<const bf16x8*>(cb + 8192 + (k2 + 1) * 32);
                }
                bf16x8 af[4];
                #pragma unroll
                for (int mt = 0; mt < 4; ++mt)
                    af[mt] = *reinterpret_cast<const bf16x8*>(
                        &h1t[(mt * 16 + l16) * 264 + k2 * 32 + quad * 8]);
                #pragma unroll
                for (int mt = 0; mt < 4; ++mt)
                    #pragma unroll
                    for (int nt = 0; nt < 2; ++nt)
                        acc2[mt][nt] = __builtin_amdgcn_mfma_f32_16x16x32_bf16(
                            af[mt], cc[nt], acc2[mt][nt], 0, 0, 0);
                cc[0] = cn[0]; cc[1] = cn[1];
            }
        }
        if (nc == 0) __syncthreads();               // h1t consumed before reuse
    }
    __syncthreads();                                // all h1t reads done
    // ---- t2 epilogue (overlays h1t) ----
    #pragma unroll
    for (int mt = 0; mt < 4; ++mt)
        #pragma unroll
        for (int nt = 0; nt < 2; ++nt)
            #pragma unroll
            for (int r = 0; r < 4; ++r) {
                int row = mt * 16 + quad * 4 + r;
                t2[row * 264 + wv * 32 + nt * 16 + l16] =
                    f2u(fmaxf(acc2[mt][nt][r], 0.f));
            }
    __syncthreads();

    // ---- heads: wave wv does rows 8wv..8wv+7 ----
    {
        float vwf[4], dwf[4];
        #pragma unroll
        for (int j = 0; j < 4; ++j) {
            vwf[j] = vw[lane + 64 * j];
            dwf[j] = dw[lane + 64 * j];
        }
        const float vbf = vb[0], dbf = db[0];
        #pragma unroll
        for (int rr = 0; rr < 8; ++rr) {
            int row = wv * 8 + rr;
            float sv = 0.f, sd = 0.f;
            #pragma unroll
            for (int j = 0; j < 4; ++j) {
                float tv = u2f(t2[row * 264 + lane + 64 * j]);
                sv += tv * vwf[j];
                sd += tv * dwf[j];
            }
            #pragma unroll
            for (int off = 32; off > 0; off >>= 1) {
                sv += __shfl_down(sv, off);
                sd += __shfl_down(sd, off);
            }
            if (lane == 0) {
                int g = blockIdx.x * 64 + row;
                out[g] = sv + vbf;
                float z = sd + dbf;
                float sig = 1.f / (1.f + __expf(-z));
                out[B_ * 16 + g] = sig * 0.4f + 0.1f;
            }
        }
    }
}

extern "C" void kernel_launch(void* const* d_in, const int* in_sizes, int n_in,
                              void* d_out, int out_size, void* d_ws, size_t ws_size,
                              hipStream_t stream) {
    const float* obs = (const float*)d_in[0];
    const float* sw1 = (const float*)d_in[1];
    const float* sb1 = (const float*)d_in[2];
    const float* sw2 = (const float*)d_in[3];
    const float* sb2 = (const float*)d_in[4];
    const float* uw1 = (const float*)d_in[5];
    const float* ub1 = (const float*)d_in[6];
    const float* uw2 = (const float*)d_in[7];
    const float* ub2 = (const float*)d_in[8];
    const float* emb = (const float*)d_in[9];
    const float* tw1 = (const float*)d_in[10];
    const float* tb1 = (const float*)d_in[11];
    const float* tw2 = (const float*)d_in[12];
    const float* tb2 = (const float*)d_in[13];
    const float* vw  = (const float*)d_in[14];
    const float* vb  = (const float*)d_in[15];
    const float* dw  = (const float*)d_in[16];
    const float* db  = (const float*)d_in[17];

    uint16_t* wsb = (uint16_t*)d_ws;

    k_front<<<256, 256, 0, stream>>>(obs, sw1, sb1, sw2, sb2,
                                     tw1, tb1, tw2, uw2, wsb);
    k_main<<<B_ / 4, 512, 0, stream>>>(obs, uw1, ub1, ub2, emb, tb2,
                                       vw, vb, dw, db, wsb, (float*)d_out);
}

// Round 11
// 241.883 us; speedup vs baseline: 1.7131x; 1.0696x over previous
//
#include <hip/hip_runtime.h>
#include <stdint.h>

// GaitnetActor B=8192, OPT=16. Round 11: fast front-end. k_conv (400 blk)
// converts all weights to bf16; k_cse (512 blk, 16 elems ea) computes
// cse[b] = se[b]@W1se^T + tb1 from bf16 weights (no inline cvt, no junk
// rows); k_main (M=64, 512 thr, 2 blocks/CU) unchanged from R10 (139 us).
// bf16 MFMA / fp32 accum. out[0:131072]=logits fp32, [131072:]=duration.

static constexpr int B_ = 8192;

typedef __attribute__((ext_vector_type(8))) short bf16x8;
typedef __attribute__((ext_vector_type(4))) float f32x4;

__device__ __forceinline__ float u2f(uint16_t u) {
    union { uint32_t i; float f; } c; c.i = (uint32_t)u << 16; return c.f;
}
__device__ __forceinline__ uint16_t f2u(float f) {
    union { float f; uint32_t i; } c; c.f = f;
    uint32_t x = c.i;
    return (uint16_t)((x + 0x7FFFu + ((x >> 16) & 1u)) >> 16);
}

// ws layout (uint16 elems)
static constexpr size_t WCSE   = 0;                    // bf16 [8192][512]
static constexpr size_t WTW1SE = 4194304;              // bf16 [512][256]
static constexpr size_t WTW1UE = WTW1SE + 131072;      // bf16 [512][128]
static constexpr size_t WTW2   = WTW1UE + 65536;       // bf16 [256][512]
static constexpr size_t WUW2   = WTW2 + 131072;        // bf16 [128][128]
static constexpr size_t WSW2   = WUW2 + 16384;         // bf16 [256][256]

// ---------------- k_conv: all weights fp32 -> bf16 (400 blocks) ------------
__global__ __launch_bounds__(256) void k_conv(
    const float* __restrict__ tw1, const float* __restrict__ tw2,
    const float* __restrict__ uw2, const float* __restrict__ sw2,
    uint16_t* __restrict__ ws)
{
    int i4 = blockIdx.x * 256 + threadIdx.x;     // one float4 per thread
    const float* src; size_t dst;
    if (i4 < 32768) {                            // tw1 se-part (k<256)
        int g = i4 * 4, n = g >> 8, k = g & 255;
        src = tw1 + (size_t)n * 384 + k;
        dst = WTW1SE + (size_t)g;
    } else if (i4 < 49152) {                     // tw1 ue-part (k>=256)
        int q = i4 - 32768, n = q >> 5, w = q & 31;
        src = tw1 + (size_t)n * 384 + 256 + w * 4;
        dst = WTW1UE + (size_t)n * 128 + w * 4;
    } else if (i4 < 81920) {
        int q = (i4 - 49152) * 4;
        src = tw2 + q; dst = WTW2 + q;
    } else if (i4 < 86016) {
        int q = (i4 - 81920) * 4;
        src = uw2 + q; dst = WUW2 + q;
    } else {
        int q = (i4 - 86016) * 4;
        src = sw2 + q; dst = WSW2 + q;
    }
    float4 v = *reinterpret_cast<const float4*>(src);
    ushort4 o;
    o.x = f2u(v.x); o.y = f2u(v.y); o.z = f2u(v.z); o.w = f2u(v.w);
    *reinterpret_cast<ushort4*>(ws + dst) = o;
}

// ---------------- k_cse: se + cse for 16 elems/block (512 blocks) ----------
__global__ __launch_bounds__(256) void k_cse(
    const float* __restrict__ obs,
    const float* __restrict__ sw1, const float* __restrict__ sb1,
    const float* __restrict__ sb2, const float* __restrict__ tb1,
    uint16_t* __restrict__ ws)
{
    __shared__ float xs[16][24];
    __shared__ uint16_t h1s[16 * 264];
    __shared__ uint16_t seL[16 * 264];
    const int t = threadIdx.x;
    const int b0 = blockIdx.x * 16;
    const uint16_t* sw2b   = ws + WSW2;
    const uint16_t* tw1seb = ws + WTW1SE;

    for (int i = t; i < 352; i += 256) {
        int e = i / 22, c = i - e * 22;
        xs[e][c] = obs[(size_t)(b0 + e) * 150 + c];
    }
    __syncthreads();
    {   // shared L1 (VALU): neuron t, 16 elems
        float w[22];
        #pragma unroll
        for (int k = 0; k < 22; ++k) w[k] = sw1[t * 22 + k];
        const float bias = sb1[t];
        #pragma unroll
        for (int e = 0; e < 16; ++e) {
            float a = bias;
            #pragma unroll
            for (int k = 0; k < 22; ++k) a += w[k] * xs[e][k];
            h1s[e * 264 + t] = f2u(fmaxf(a, 0.f));
        }
    }
    __syncthreads();
    const int wv = t >> 6, lane = t & 63, quad = lane >> 4, l16 = lane & 15;
    {   // shared L2 (MFMA): M=16, N=256 (wave N=64), K=256 -> seL
        f32x4 acc[4];
        #pragma unroll
        for (int nt = 0; nt < 4; ++nt) {
            float bv = sb2[wv * 64 + nt * 16 + l16];
            acc[nt] = {bv, bv, bv, bv};
        }
        const uint16_t* bb = sw2b + (size_t)(wv * 64 + l16) * 256 + quad * 8;
        bf16x8 bc[4], bn[4];
        #pragma unroll
        for (int nt = 0; nt < 4; ++nt)
            bc[nt] = *reinterpret_cast<const bf16x8*>(bb + nt * 4096);
        #pragma unroll
        for (int kk = 0; kk < 8; ++kk) {
            if (kk < 7) {
                #pragma unroll
                for (int nt = 0; nt < 4; ++nt)
                    bn[nt] = *reinterpret_cast<const bf16x8*>(
                        bb + nt * 4096 + (kk + 1) * 32);
            }
            bf16x8 af = *reinterpret_cast<const bf16x8*>(
                &h1s[l16 * 264 + kk * 32 + quad * 8]);
            #pragma unroll
            for (int nt = 0; nt < 4; ++nt)
                acc[nt] = __builtin_amdgcn_mfma_f32_16x16x32_bf16(
                    af, bc[nt], acc[nt], 0, 0, 0);
            #pragma unroll
            for (int nt = 0; nt < 4; ++nt) bc[nt] = bn[nt];
        }
        #pragma unroll
        for (int nt = 0; nt < 4; ++nt)
            #pragma unroll
            for (int r = 0; r < 4; ++r)
                seL[(quad * 4 + r) * 264 + wv * 64 + nt * 16 + l16] =
                    f2u(fmaxf(acc[nt][r], 0.f));
    }
    __syncthreads();
    {   // cse (MFMA): M=16, N=512 (wave N=128), K=256, no relu -> ws
        f32x4 acc[8];
        #pragma unroll
        for (int nt = 0; nt < 8; ++nt) {
            float bv = tb1[wv * 128 + nt * 16 + l16];
            acc[nt] = {bv, bv, bv, bv};
        }
        const uint16_t* bb = tw1seb + (size_t)(wv * 128 + l16) * 256 + quad * 8;
        bf16x8 bc[8], bn[8];
        #pragma unroll
        for (int nt = 0; nt < 8; ++nt)
            bc[nt] = *reinterpret_cast<const bf16x8*>(bb + nt * 4096);
        #pragma unroll
        for (int kk = 0; kk < 8; ++kk) {
            if (kk < 7) {
                #pragma unroll
                for (int nt = 0; nt < 8; ++nt)
                    bn[nt] = *reinterpret_cast<const bf16x8*>(
                        bb + nt * 4096 + (kk + 1) * 32);
            }
            bf16x8 af = *reinterpret_cast<const bf16x8*>(
                &seL[l16 * 264 + kk * 32 + quad * 8]);
            #pragma unroll
            for (int nt = 0; nt < 8; ++nt)
                acc[nt] = __builtin_amdgcn_mfma_f32_16x16x32_bf16(
                    af, bc[nt], acc[nt], 0, 0, 0);
            #pragma unroll
            for (int nt = 0; nt < 8; ++nt) bc[nt] = bn[nt];
        }
        #pragma unroll
        for (int nt = 0; nt < 8; ++nt)
            #pragma unroll
            for (int r = 0; r < 4; ++r)
                ws[WCSE + (size_t)(b0 + quad * 4 + r) * 512 +
                   wv * 128 + nt * 16 + l16] = f2u(acc[nt][r]);
    }
}

// ---------------- k_main (unchanged from R10, new ws offsets) --------------
static constexpr int UQ_OFF   = 0;
static constexpr int NOOP_OFF = 2112;
static constexpr int CSE_OFF  = 2368;
static constexpr int H1U_OFF  = 6464;
static constexpr int UET_OFF  = 23872;
static constexpr int H1T_OFF  = 41280;
static constexpr int SMEM_SZ  = 75072;

__global__ __launch_bounds__(512, 4) void k_main(
    const float* __restrict__ obs,
    const float* __restrict__ uw1, const float* __restrict__ ub1,
    const float* __restrict__ ub2, const float* __restrict__ emb,
    const float* __restrict__ tb2,
    const float* __restrict__ vw,  const float* __restrict__ vb,
    const float* __restrict__ dw,  const float* __restrict__ db,
    const uint16_t* __restrict__ wsb,
    float* __restrict__ out)
{
    __shared__ __align__(16) char smem[SMEM_SZ];
    float*    uq    = (float*)(smem + UQ_OFF);
    float*    noopf = (float*)(smem + NOOP_OFF);
    uint16_t* cseL  = (uint16_t*)(smem + CSE_OFF);
    uint16_t* h1u   = (uint16_t*)(smem + H1U_OFF);
    uint16_t* uet   = (uint16_t*)(smem + UET_OFF);
    uint16_t* h1t   = (uint16_t*)(smem + H1T_OFF);
    uint16_t* t2    = h1t;

    const int t    = threadIdx.x;
    const int wv   = t >> 6;
    const int lane = t & 63;
    const int quad = lane >> 4;
    const int l16  = lane & 15;
    const int b0   = blockIdx.x * 4;

    const uint16_t* csep  = wsb + WCSE;
    const uint16_t* tw1ue = wsb + WTW1UE;
    const uint16_t* tw2b  = wsb + WTW2;
    const uint16_t* uw2b  = wsb + WUW2;

    // ---- stage 1: uniq obs cols, noop flags, cse rows ----
    {
        int e = t >> 7, c = t & 127;
        uq[e * 132 + c] = obs[(size_t)(b0 + e) * 150 + 22 + c];
        #pragma unroll
        for (int ii = 0; ii < 2; ++ii) {
            int i = t + ii * 512;
            int ee = i >> 8, cc = i & 255;
            ((uint32_t*)cseL)[ee * 256 + cc] =
                ((const uint32_t*)(csep + (size_t)(b0 + ee) * 512))[cc];
        }
        if (t < 64) {
            int ee = t >> 4, o = t & 15;
            noopf[t] = (obs[(size_t)(b0 + ee) * 150 + 22 + o * 8] == 1.0f) ? 1.0f : 0.0f;
        }
    }
    __syncthreads();

    // ---- stage 2: unique L1 (VALU): 64 rows x 128 neurons ----
    {
        const int n = t & 127, h = t >> 7;
        float w[8];
        #pragma unroll
        for (int k = 0; k < 8; ++k) w[k] = uw1[n * 8 + k];
        const float bias = ub1[n];
        #pragma unroll
        for (int ii = 0; ii < 16; ++ii) {
            int row = h * 16 + ii;
            const float4* xp = (const float4*)&uq[h * 132 + ii * 8];
            float4 xa = xp[0], xb = xp[1];
            float a = bias + w[0] * xa.x + w[1] * xa.y + w[2] * xa.z + w[3] * xa.w
                           + w[4] * xb.x + w[5] * xb.y + w[6] * xb.z + w[7] * xb.w;
            h1u[row * 136 + n] = f2u(fmaxf(a, 0.f));
        }
    }
    __syncthreads();

    // ---- stage 3: unique L2 via MFMA (wave: M=64 x N=16), K=128 -> uet ----
    {
        const int n = wv * 16 + l16;
        const float bv = ub2[n];
        const float ev = emb[n];
        f32x4 acc[4];
        #pragma unroll
        for (int mt = 0; mt < 4; ++mt) acc[mt] = {bv, bv, bv, bv};
        #pragma unroll
        for (int kk = 0; kk < 4; ++kk) {
            bf16x8 bf = *reinterpret_cast<const bf16x8*>(
                &uw2b[(size_t)n * 128 + kk * 32 + quad * 8]);
            #pragma unroll
            for (int mt = 0; mt < 4; ++mt) {
                bf16x8 af = *reinterpret_cast<const bf16x8*>(
                    &h1u[(mt * 16 + l16) * 136 + kk * 32 + quad * 8]);
                acc[mt] = __builtin_amdgcn_mfma_f32_16x16x32_bf16(af, bf, acc[mt], 0, 0, 0);
            }
        }
        #pragma unroll
        for (int mt = 0; mt < 4; ++mt)
            #pragma unroll
            for (int r = 0; r < 4; ++r) {
                int row = mt * 16 + quad * 4 + r;
                float v = (noopf[row] != 0.0f) ? ev : fmaxf(acc[mt][r], 0.f);
                uet[row * 136 + n] = f2u(v);
            }
    }
    __syncthreads();

    // ---- trunk: 2 N-chunks of 256; L1 (K=128, acc init = cse) -> L2 ----
    f32x4 acc2[4][2];
    #pragma unroll
    for (int nt = 0; nt < 2; ++nt) {
        float bv = tb2[wv * 32 + nt * 16 + l16];
        #pragma unroll
        for (int mt = 0; mt < 4; ++mt) acc2[mt][nt] = {bv, bv, bv, bv};
    }

    #pragma unroll
    for (int nc = 0; nc < 2; ++nc) {
        {
            f32x4 acc1[4][2];
            #pragma unroll
            for (int nt = 0; nt < 2; ++nt) {
                int n = nc * 256 + wv * 32 + nt * 16 + l16;
                #pragma unroll
                for (int mt = 0; mt < 4; ++mt) {
                    float v = u2f(cseL[mt * 512 + n]);
                    acc1[mt][nt] = {v, v, v, v};
                }
            }
            const uint16_t* bb = tw1ue + (size_t)(nc * 256 + wv * 32 + l16) * 128
                                 + quad * 8;
            bf16x8 bc[2], bn[2];
            bc[0] = *reinterpret_cast<const bf16x8*>(bb);
            bc[1] = *reinterpret_cast<const bf16x8*>(bb + 2048);
            #pragma unroll
            for (int kk = 0; kk < 4; ++kk) {
                if (kk < 3) {
                    bn[0] = *reinterpret_cast<const bf16x8*>(bb + (kk + 1) * 32);
                    bn[1] = *reinterpret_cast<const bf16x8*>(bb + 2048 + (kk + 1) * 32);
                }
                bf16x8 af[4];
                #pragma unroll
                for (int mt = 0; mt < 4; ++mt)
                    af[mt] = *reinterpret_cast<const bf16x8*>(
                        &uet[(mt * 16 + l16) * 136 + kk * 32 + quad * 8]);
                #pragma unroll
                for (int mt = 0; mt < 4; ++mt)
                    #pragma unroll
                    for (int nt = 0; nt < 2; ++nt)
                        acc1[mt][nt] = __builtin_amdgcn_mfma_f32_16x16x32_bf16(
                            af[mt], bc[nt], acc1[mt][nt], 0, 0, 0);
                bc[0] = bn[0]; bc[1] = bn[1];
            }
            #pragma unroll
            for (int mt = 0; mt < 4; ++mt)
                #pragma unroll
                for (int nt = 0; nt < 2; ++nt)
                    #pragma unroll
                    for (int r = 0; r < 4; ++r) {
                        int row = mt * 16 + quad * 4 + r;
                        h1t[row * 264 + wv * 32 + nt * 16 + l16] =
                            f2u(fmaxf(acc1[mt][nt][r], 0.f));
                    }
        }
        __syncthreads();
        {
            const uint16_t* cb = tw2b + (size_t)(wv * 32 + l16) * 512 + nc * 256
                                 + quad * 8;
            bf16x8 cc[2], cn[2];
            cc[0] = *reinterpret_cast<const bf16x8*>(cb);
            cc[1] = *reinterpret_cast<const bf16x8*>(cb + 8192);
            #pragma unroll
            for (int k2 = 0; k2 < 8; ++k2) {
                if (k2 < 7) {
                    cn[0] = *reinterpret_cast<const bf16x8*>(cb + (k2 + 1) * 32);
                    cn[1] = *reinterpret_cast<const bf16x8*>(cb + 8192 + (k2 + 1) * 32);
                }
                bf16x8 af[4];
                #pragma unroll
                for (int mt = 0; mt < 4; ++mt)
                    af[mt] = *reinterpret_cast<const bf16x8*>(
                        &h1t[(mt * 16 + l16) * 264 + k2 * 32 + quad * 8]);
                #pragma unroll
                for (int mt = 0; mt < 4; ++mt)
                    #pragma unroll
                    for (int nt = 0; nt < 2; ++nt)
                        acc2[mt][nt] = __builtin_amdgcn_mfma_f32_16x16x32_bf16(
                            af[mt], cc[nt], acc2[mt][nt], 0, 0, 0);
                cc[0] = cn[0]; cc[1] = cn[1];
            }
        }
        if (nc == 0) __syncthreads();
    }
    __syncthreads();
    #pragma unroll
    for (int mt = 0; mt < 4; ++mt)
        #pragma unroll
        for (int nt = 0; nt < 2; ++nt)
            #pragma unroll
            for (int r = 0; r < 4; ++r) {
                int row = mt * 16 + quad * 4 + r;
                t2[row * 264 + wv * 32 + nt * 16 + l16] =
                    f2u(fmaxf(acc2[mt][nt][r], 0.f));
            }
    __syncthreads();

    // ---- heads ----
    {
        float vwf[4], dwf[4];
        #pragma unroll
        for (int j = 0; j < 4; ++j) {
            vwf[j] = vw[lane + 64 * j];
            dwf[j] = dw[lane + 64 * j];
        }
        const float vbf = vb[0], dbf = db[0];
        #pragma unroll
        for (int rr = 0; rr < 8; ++rr) {
            int row = wv * 8 + rr;
            float sv = 0.f, sd = 0.f;
            #pragma unroll
            for (int j = 0; j < 4; ++j) {
                float tv = u2f(t2[row * 264 + lane + 64 * j]);
                sv += tv * vwf[j];
                sd += tv * dwf[j];
            }
            #pragma unroll
            for (int off = 32; off > 0; off >>= 1) {
                sv += __shfl_down(sv, off);
                sd += __shfl_down(sd, off);
            }
            if (lane == 0) {
                int g = blockIdx.x * 64 + row;
                out[g] = sv + vbf;
                float z = sd + dbf;
                float sig = 1.f / (1.f + __expf(-z));
                out[B_ * 16 + g] = sig * 0.4f + 0.1f;
            }
        }
    }
}

extern "C" void kernel_launch(void* const* d_in, const int* in_sizes, int n_in,
                              void* d_out, int out_size, void* d_ws, size_t ws_size,
                              hipStream_t stream) {
    const float* obs = (const float*)d_in[0];
    const float* sw1 = (const float*)d_in[1];
    const float* sb1 = (const float*)d_in[2];
    const float* sw2 = (const float*)d_in[3];
    const float* sb2 = (const float*)d_in[4];
    const float* uw1 = (const float*)d_in[5];
    const float* ub1 = (const float*)d_in[6];
    const float* uw2 = (const float*)d_in[7];
    const float* ub2 = (const float*)d_in[8];
    const float* emb = (const float*)d_in[9];
    const float* tw1 = (const float*)d_in[10];
    const float* tb1 = (const float*)d_in[11];
    const float* tw2 = (const float*)d_in[12];
    const float* tb2 = (const float*)d_in[13];
    const float* vw  = (const float*)d_in[14];
    const float* vb  = (const float*)d_in[15];
    const float* dw  = (const float*)d_in[16];
    const float* db  = (const float*)d_in[17];

    uint16_t* wsb = (uint16_t*)d_ws;

    k_conv<<<400, 256, 0, stream>>>(tw1, tw2, uw2, sw2, wsb);
    k_cse<<<512, 256, 0, stream>>>(obs, sw1, sb1, sb2, tb1, wsb);
    k_main<<<B_ / 4, 512, 0, stream>>>(obs, uw1, ub1, ub2, emb, tb2,
                                       vw, vb, dw, db, wsb, (float*)d_out);
}

// Round 12
// 239.518 us; speedup vs baseline: 1.7300x; 1.0099x over previous
//
#include <hip/hip_runtime.h>
#include <stdint.h>

// GaitnetActor B=8192, OPT=16. Round 12: k_cse at 512 thr (2x TLP);
// k_main uniq-L1 moved to MFMA (uqb/uw1b bf16 zero-padded K=32);
// k_conv also emits uw1b. k_main trunk structure unchanged (R10/R11).
// bf16 MFMA / fp32 accum. out[0:131072]=logits fp32, [131072:]=duration.

static constexpr int B_ = 8192;

typedef __attribute__((ext_vector_type(8))) short bf16x8;
typedef __attribute__((ext_vector_type(4))) float f32x4;

__device__ __forceinline__ float u2f(uint16_t u) {
    union { uint32_t i; float f; } c; c.i = (uint32_t)u << 16; return c.f;
}
__device__ __forceinline__ uint16_t f2u(float f) {
    union { float f; uint32_t i; } c; c.f = f;
    uint32_t x = c.i;
    return (uint16_t)((x + 0x7FFFu + ((x >> 16) & 1u)) >> 16);
}

// ws layout (uint16 elems)
static constexpr size_t WCSE   = 0;                    // bf16 [8192][512]
static constexpr size_t WTW1SE = 4194304;              // bf16 [512][256]
static constexpr size_t WTW1UE = WTW1SE + 131072;      // bf16 [512][128]
static constexpr size_t WTW2   = WTW1UE + 65536;       // bf16 [256][512]
static constexpr size_t WUW2   = WTW2 + 131072;        // bf16 [128][128]
static constexpr size_t WSW2   = WUW2 + 16384;         // bf16 [256][256]
static constexpr size_t WUW1B  = WSW2 + 65536;         // bf16 [128][32] 0-pad

// ---------------- k_conv: all weights fp32 -> bf16 (404 blocks) ------------
__global__ __launch_bounds__(256) void k_conv(
    const float* __restrict__ tw1, const float* __restrict__ tw2,
    const float* __restrict__ uw2, const float* __restrict__ sw2,
    const float* __restrict__ uw1, uint16_t* __restrict__ ws)
{
    int i4 = blockIdx.x * 256 + threadIdx.x;
    if (i4 >= 102400) {                          // uw1b: zero-padded K=32
        int q = i4 - 102400;                     // [0,1024)
        int n = q >> 3, k0 = (q & 7) * 4;
        ushort4 o = {0, 0, 0, 0};
        if (k0 < 8) {
            float4 v = *reinterpret_cast<const float4*>(uw1 + n * 8 + k0);
            o.x = f2u(v.x); o.y = f2u(v.y); o.z = f2u(v.z); o.w = f2u(v.w);
        }
        *reinterpret_cast<ushort4*>(ws + WUW1B + n * 32 + k0) = o;
        return;
    }
    const float* src; size_t dst;
    if (i4 < 32768) {                            // tw1 se-part (k<256)
        int g = i4 * 4, n = g >> 8, k = g & 255;
        src = tw1 + (size_t)n * 384 + k;
        dst = WTW1SE + (size_t)g;
    } else if (i4 < 49152) {                     // tw1 ue-part (k>=256)
        int q = i4 - 32768, n = q >> 5, w = q & 31;
        src = tw1 + (size_t)n * 384 + 256 + w * 4;
        dst = WTW1UE + (size_t)n * 128 + w * 4;
    } else if (i4 < 81920) {
        int q = (i4 - 49152) * 4;
        src = tw2 + q; dst = WTW2 + q;
    } else if (i4 < 86016) {
        int q = (i4 - 81920) * 4;
        src = uw2 + q; dst = WUW2 + q;
    } else {
        int q = (i4 - 86016) * 4;
        src = sw2 + q; dst = WSW2 + q;
    }
    float4 v = *reinterpret_cast<const float4*>(src);
    ushort4 o;
    o.x = f2u(v.x); o.y = f2u(v.y); o.z = f2u(v.z); o.w = f2u(v.w);
    *reinterpret_cast<ushort4*>(ws + dst) = o;
}

// ---------------- k_cse: se + cse, 16 elems/block, 512 thr (512 blocks) ----
__global__ __launch_bounds__(512) void k_cse(
    const float* __restrict__ obs,
    const float* __restrict__ sw1, const float* __restrict__ sb1,
    const float* __restrict__ sb2, const float* __restrict__ tb1,
    uint16_t* __restrict__ ws)
{
    __shared__ float xs[16][24];
    __shared__ uint16_t h1s[16 * 264];
    __shared__ uint16_t seL[16 * 264];
    const int t = threadIdx.x;
    const int b0 = blockIdx.x * 16;
    const uint16_t* sw2b   = ws + WSW2;
    const uint16_t* tw1seb = ws + WTW1SE;

    if (t < 352) {
        int e = t / 22, c = t - e * 22;
        xs[e][c] = obs[(size_t)(b0 + e) * 150 + c];
    }
    __syncthreads();
    {   // shared L1 (VALU): neuron t&255, 8 elems each
        const int n = t & 255;
        float w[22];
        #pragma unroll
        for (int k = 0; k < 22; ++k) w[k] = sw1[n * 22 + k];
        const float bias = sb1[n];
        #pragma unroll
        for (int ii = 0; ii < 8; ++ii) {
            int e = (t >> 8) * 8 + ii;
            float a = bias;
            #pragma unroll
            for (int k = 0; k < 22; ++k) a += w[k] * xs[e][k];
            h1s[e * 264 + n] = f2u(fmaxf(a, 0.f));
        }
    }
    __syncthreads();
    const int wv = t >> 6, lane = t & 63, quad = lane >> 4, l16 = lane & 15;
    {   // shared L2 (MFMA): M=16, wave N=32, K=256 -> seL
        f32x4 acc[2];
        #pragma unroll
        for (int nt = 0; nt < 2; ++nt) {
            float bv = sb2[wv * 32 + nt * 16 + l16];
            acc[nt] = {bv, bv, bv, bv};
        }
        const uint16_t* bb = sw2b + (size_t)(wv * 32 + l16) * 256 + quad * 8;
        bf16x8 bc[2], bn[2];
        bc[0] = *reinterpret_cast<const bf16x8*>(bb);
        bc[1] = *reinterpret_cast<const bf16x8*>(bb + 4096);
        #pragma unroll
        for (int kk = 0; kk < 8; ++kk) {
            if (kk < 7) {
                bn[0] = *reinterpret_cast<const bf16x8*>(bb + (kk + 1) * 32);
                bn[1] = *reinterpret_cast<const bf16x8*>(bb + 4096 + (kk + 1) * 32);
            }
            bf16x8 af = *reinterpret_cast<const bf16x8*>(
                &h1s[l16 * 264 + kk * 32 + quad * 8]);
            #pragma unroll
            for (int nt = 0; nt < 2; ++nt)
                acc[nt] = __builtin_amdgcn_mfma_f32_16x16x32_bf16(
                    af, bc[nt], acc[nt], 0, 0, 0);
            bc[0] = bn[0]; bc[1] = bn[1];
        }
        #pragma unroll
        for (int nt = 0; nt < 2; ++nt)
            #pragma unroll
            for (int r = 0; r < 4; ++r)
                seL[(quad * 4 + r) * 264 + wv * 32 + nt * 16 + l16] =
                    f2u(fmaxf(acc[nt][r], 0.f));
    }
    __syncthreads();
    {   // cse (MFMA): M=16, wave N=64, K=256, no relu -> ws
        f32x4 acc[4];
        #pragma unroll
        for (int nt = 0; nt < 4; ++nt) {
            float bv = tb1[wv * 64 + nt * 16 + l16];
            acc[nt] = {bv, bv, bv, bv};
        }
        const uint16_t* bb = tw1seb + (size_t)(wv * 64 + l16) * 256 + quad * 8;
        bf16x8 bc[4], bn[4];
        #pragma unroll
        for (int nt = 0; nt < 4; ++nt)
            bc[nt] = *reinterpret_cast<const bf16x8*>(bb + nt * 4096);
        #pragma unroll
        for (int kk = 0; kk < 8; ++kk) {
            if (kk < 7) {
                #pragma unroll
                for (int nt = 0; nt < 4; ++nt)
                    bn[nt] = *reinterpret_cast<const bf16x8*>(
                        bb + nt * 4096 + (kk + 1) * 32);
            }
            bf16x8 af = *reinterpret_cast<const bf16x8*>(
                &seL[l16 * 264 + kk * 32 + quad * 8]);
            #pragma unroll
            for (int nt = 0; nt < 4; ++nt)
                acc[nt] = __builtin_amdgcn_mfma_f32_16x16x32_bf16(
                    af, bc[nt], acc[nt], 0, 0, 0);
            #pragma unroll
            for (int nt = 0; nt < 4; ++nt) bc[nt] = bn[nt];
        }
        #pragma unroll
        for (int nt = 0; nt < 4; ++nt)
            #pragma unroll
            for (int r = 0; r < 4; ++r)
                ws[WCSE + (size_t)(b0 + quad * 4 + r) * 512 +
                   wv * 64 + nt * 16 + l16] = f2u(acc[nt][r]);
    }
}

// ---------------- k_main -------------------------------------------------
// LDS (bytes): uqb bf16[64][40] 0..5120 | noop f32[64] @5120 | cse bf16[4][512]
// @5376 | h1u bf16[64][136] @9472 | uet @26880 | h1t bf16[64][264] @44288
// (t2 overlays) -> 78080 B, 2 blocks/CU.
static constexpr int UQB_OFF  = 0;
static constexpr int NOOP_OFF = 5120;
static constexpr int CSE_OFF  = 5376;
static constexpr int H1U_OFF  = 9472;
static constexpr int UET_OFF  = 26880;
static constexpr int H1T_OFF  = 44288;
static constexpr int SMEM_SZ  = 78080;

__global__ __launch_bounds__(512, 4) void k_main(
    const float* __restrict__ obs,
    const float* __restrict__ ub1,
    const float* __restrict__ ub2, const float* __restrict__ emb,
    const float* __restrict__ tb2,
    const float* __restrict__ vw,  const float* __restrict__ vb,
    const float* __restrict__ dw,  const float* __restrict__ db,
    const uint16_t* __restrict__ wsb,
    float* __restrict__ out)
{
    __shared__ __align__(16) char smem[SMEM_SZ];
    uint16_t* uqb   = (uint16_t*)(smem + UQB_OFF);
    float*    noopf = (float*)(smem + NOOP_OFF);
    uint16_t* cseL  = (uint16_t*)(smem + CSE_OFF);
    uint16_t* h1u   = (uint16_t*)(smem + H1U_OFF);
    uint16_t* uet   = (uint16_t*)(smem + UET_OFF);
    uint16_t* h1t   = (uint16_t*)(smem + H1T_OFF);
    uint16_t* t2    = h1t;

    const int t    = threadIdx.x;
    const int wv   = t >> 6;
    const int lane = t & 63;
    const int quad = lane >> 4;
    const int l16  = lane & 15;
    const int b0   = blockIdx.x * 4;

    const uint16_t* csep  = wsb + WCSE;
    const uint16_t* tw1ue = wsb + WTW1UE;
    const uint16_t* tw2b  = wsb + WTW2;
    const uint16_t* uw2b  = wsb + WUW2;
    const uint16_t* uw1b  = wsb + WUW1B;

    // ---- stage 1: uqb bf16 [64][40] (K=32 zero-padded), noop, cse rows ----
    {
        int r = t >> 3, q = t & 7;               // row 0..63, k-quad 0..7
        int e = r >> 4, o = r & 15;
        ushort4 ov = {0, 0, 0, 0};
        if (q < 2) {                             // cols 0..7 real (8B-aligned)
            const float2* sp = reinterpret_cast<const float2*>(
                &obs[(size_t)(b0 + e) * 150 + 22 + o * 8 + q * 4]);
            float2 a = sp[0], b = sp[1];
            ov.x = f2u(a.x); ov.y = f2u(a.y); ov.z = f2u(b.x); ov.w = f2u(b.y);
        }
        *reinterpret_cast<ushort4*>(&uqb[r * 40 + q * 4]) = ov;
        #pragma unroll
        for (int ii = 0; ii < 2; ++ii) {         // cse rows: 1024 dwords
            int i = t + ii * 512;
            int ee = i >> 8, cc = i & 255;
            ((uint32_t*)cseL)[ee * 256 + cc] =
                ((const uint32_t*)(csep + (size_t)(b0 + ee) * 512))[cc];
        }
        if (t < 64) {
            int ee = t >> 4, oo = t & 15;
            noopf[t] = (obs[(size_t)(b0 + ee) * 150 + 22 + oo * 8] == 1.0f) ? 1.0f : 0.0f;
        }
    }
    __syncthreads();

    // ---- stage 2: unique L1 via MFMA (wave: M=64 x N=16, K=32) ----
    {
        const int n = wv * 16 + l16;
        const float bv = ub1[n];
        f32x4 acc[4];
        #pragma unroll
        for (int mt = 0; mt < 4; ++mt) acc[mt] = {bv, bv, bv, bv};
        bf16x8 bf = *reinterpret_cast<const bf16x8*>(&uw1b[n * 32 + quad * 8]);
        #pragma unroll
        for (int mt = 0; mt < 4; ++mt) {
            bf16x8 af = *reinterpret_cast<const bf16x8*>(
                &uqb[(mt * 16 + l16) * 40 + quad * 8]);
            acc[mt] = __builtin_amdgcn_mfma_f32_16x16x32_bf16(af, bf, acc[mt], 0, 0, 0);
        }
        #pragma unroll
        for (int mt = 0; mt < 4; ++mt)
            #pragma unroll
            for (int r = 0; r < 4; ++r) {
                int row = mt * 16 + quad * 4 + r;
                h1u[row * 136 + n] = f2u(fmaxf(acc[mt][r], 0.f));
            }
    }
    __syncthreads();

    // ---- stage 3: unique L2 via MFMA (wave: M=64 x N=16), K=128 -> uet ----
    {
        const int n = wv * 16 + l16;
        const float bv = ub2[n];
        const float ev = emb[n];
        f32x4 acc[4];
        #pragma unroll
        for (int mt = 0; mt < 4; ++mt) acc[mt] = {bv, bv, bv, bv};
        #pragma unroll
        for (int kk = 0; kk < 4; ++kk) {
            bf16x8 bf = *reinterpret_cast<const bf16x8*>(
                &uw2b[(size_t)n * 128 + kk * 32 + quad * 8]);
            #pragma unroll
            for (int mt = 0; mt < 4; ++mt) {
                bf16x8 af = *reinterpret_cast<const bf16x8*>(
                    &h1u[(mt * 16 + l16) * 136 + kk * 32 + quad * 8]);
                acc[mt] = __builtin_amdgcn_mfma_f32_16x16x32_bf16(af, bf, acc[mt], 0, 0, 0);
            }
        }
        #pragma unroll
        for (int mt = 0; mt < 4; ++mt)
            #pragma unroll
            for (int r = 0; r < 4; ++r) {
                int row = mt * 16 + quad * 4 + r;
                float v = (noopf[row] != 0.0f) ? ev : fmaxf(acc[mt][r], 0.f);
                uet[row * 136 + n] = f2u(v);
            }
    }
    __syncthreads();

    // ---- trunk: 2 N-chunks of 256; L1 (K=128, acc init = cse) -> L2 ----
    f32x4 acc2[4][2];
    #pragma unroll
    for (int nt = 0; nt < 2; ++nt) {
        float bv = tb2[wv * 32 + nt * 16 + l16];
        #pragma unroll
        for (int mt = 0; mt < 4; ++mt) acc2[mt][nt] = {bv, bv, bv, bv};
    }

    #pragma unroll
    for (int nc = 0; nc < 2; ++nc) {
        {
            f32x4 acc1[4][2];
            #pragma unroll
            for (int nt = 0; nt < 2; ++nt) {
                int n = nc * 256 + wv * 32 + nt * 16 + l16;
                #pragma unroll
                for (int mt = 0; mt < 4; ++mt) {
                    float v = u2f(cseL[mt * 512 + n]);
                    acc1[mt][nt] = {v, v, v, v};
                }
            }
            const uint16_t* bb = tw1ue + (size_t)(nc * 256 + wv * 32 + l16) * 128
                                 + quad * 8;
            bf16x8 bc[2], bn[2];
            bc[0] = *reinterpret_cast<const bf16x8*>(bb);
            bc[1] = *reinterpret_cast<const bf16x8*>(bb + 2048);
            #pragma unroll
            for (int kk = 0; kk < 4; ++kk) {
                if (kk < 3) {
                    bn[0] = *reinterpret_cast<const bf16x8*>(bb + (kk + 1) * 32);
                    bn[1] = *reinterpret_cast<const bf16x8*>(bb + 2048 + (kk + 1) * 32);
                }
                bf16x8 af[4];
                #pragma unroll
                for (int mt = 0; mt < 4; ++mt)
                    af[mt] = *reinterpret_cast<const bf16x8*>(
                        &uet[(mt * 16 + l16) * 136 + kk * 32 + quad * 8]);
                #pragma unroll
                for (int mt = 0; mt < 4; ++mt)
                    #pragma unroll
                    for (int nt = 0; nt < 2; ++nt)
                        acc1[mt][nt] = __builtin_amdgcn_mfma_f32_16x16x32_bf16(
                            af[mt], bc[nt], acc1[mt][nt], 0, 0, 0);
                bc[0] = bn[0]; bc[1] = bn[1];
            }
            #pragma unroll
            for (int mt = 0; mt < 4; ++mt)
                #pragma unroll
                for (int nt = 0; nt < 2; ++nt)
                    #pragma unroll
                    for (int r = 0; r < 4; ++r) {
                        int row = mt * 16 + quad * 4 + r;
                        h1t[row * 264 + wv * 32 + nt * 16 + l16] =
                            f2u(fmaxf(acc1[mt][nt][r], 0.f));
                    }
        }
        __syncthreads();
        {
            const uint16_t* cb = tw2b + (size_t)(wv * 32 + l16) * 512 + nc * 256
                                 + quad * 8;
            bf16x8 cc[2], cn[2];
            cc[0] = *reinterpret_cast<const bf16x8*>(cb);
            cc[1] = *reinterpret_cast<const bf16x8*>(cb + 8192);
            #pragma unroll
            for (int k2 = 0; k2 < 8; ++k2) {
                if (k2 < 7) {
                    cn[0] = *reinterpret_cast<const bf16x8*>(cb + (k2 + 1) * 32);
                    cn[1] = *reinterpret_cast<const bf16x8*>(cb + 8192 + (k2 + 1) * 32);
                }
                bf16x8 af[4];
                #pragma unroll
                for (int mt = 0; mt < 4; ++mt)
                    af[mt] = *reinterpret_cast<const bf16x8*>(
                        &h1t[(mt * 16 + l16) * 264 + k2 * 32 + quad * 8]);
                #pragma unroll
                for (int mt = 0; mt < 4; ++mt)
                    #pragma unroll
                    for (int nt = 0; nt < 2; ++nt)
                        acc2[mt][nt] = __builtin_amdgcn_mfma_f32_16x16x32_bf16(
                            af[mt], cc[nt], acc2[mt][nt], 0, 0, 0);
                cc[0] = cn[0]; cc[1] = cn[1];
            }
        }
        if (nc == 0) __syncthreads();
    }
    __syncthreads();
    #pragma unroll
    for (int mt = 0; mt < 4; ++mt)
        #pragma unroll
        for (int nt = 0; nt < 2; ++nt)
            #pragma unroll
            for (int r = 0; r < 4; ++r) {
                int row = mt * 16 + quad * 4 + r;
                t2[row * 264 + wv * 32 + nt * 16 + l16] =
                    f2u(fmaxf(acc2[mt][nt][r], 0.f));
            }
    __syncthreads();

    // ---- heads ----
    {
        float vwf[4], dwf[4];
        #pragma unroll
        for (int j = 0; j < 4; ++j) {
            vwf[j] = vw[lane + 64 * j];
            dwf[j] = dw[lane + 64 * j];
        }
        const float vbf = vb[0], dbf = db[0];
        #pragma unroll
        for (int rr = 0; rr < 8; ++rr) {
            int row = wv * 8 + rr;
            float sv = 0.f, sd = 0.f;
            #pragma unroll
            for (int j = 0; j < 4; ++j) {
                float tv = u2f(t2[row * 264 + lane + 64 * j]);
                sv += tv * vwf[j];
                sd += tv * dwf[j];
            }
            #pragma unroll
            for (int off = 32; off > 0; off >>= 1) {
                sv += __shfl_down(sv, off);
                sd += __shfl_down(sd, off);
            }
            if (lane == 0) {
                int g = blockIdx.x * 64 + row;
                out[g] = sv + vbf;
                float z = sd + dbf;
                float sig = 1.f / (1.f + __expf(-z));
                out[B_ * 16 + g] = sig * 0.4f + 0.1f;
            }
        }
    }
}

extern "C" void kernel_launch(void* const* d_in, const int* in_sizes, int n_in,
                              void* d_out, int out_size, void* d_ws, size_t ws_size,
                              hipStream_t stream) {
    const float* obs = (const float*)d_in[0];
    const float* sw1 = (const float*)d_in[1];
    const float* sb1 = (const float*)d_in[2];
    const float* sw2 = (const float*)d_in[3];
    const float* sb2 = (const float*)d_in[4];
    const float* uw1 = (const float*)d_in[5];
    const float* ub1 = (const float*)d_in[6];
    const float* uw2 = (const float*)d_in[7];
    const float* ub2 = (const float*)d_in[8];
    const float* emb = (const float*)d_in[9];
    const float* tw1 = (const float*)d_in[10];
    const float* tb1 = (const float*)d_in[11];
    const float* tw2 = (const float*)d_in[12];
    const float* tb2 = (const float*)d_in[13];
    const float* vw  = (const float*)d_in[14];
    const float* vb  = (const float*)d_in[15];
    const float* dw  = (const float*)d_in[16];
    const float* db  = (const float*)d_in[17];

    uint16_t* wsb = (uint16_t*)d_ws;

    k_conv<<<404, 256, 0, stream>>>(tw1, tw2, uw2, sw2, uw1, wsb);
    k_cse<<<512, 512, 0, stream>>>(obs, sw1, sb1, sb2, tb1, wsb);
    k_main<<<B_ / 4, 512, 0, stream>>>(obs, ub1, ub2, emb, tb2,
                                       vw, vb, dw, db, wsb, (float*)d_out);
}